// Round 14
// baseline (166.002 us; speedup 1.0000x reference)
//
#include <hip/hip_runtime.h>
#include <stdint.h>

#define B_SZ 8192
#define N_SZ 256
#define H_SZ 2048
#define LOG2PI_F 1.8378770664093453f
#define BETA_F 0.99f

typedef unsigned short ushort_t;
typedef __attribute__((ext_vector_type(8))) __bf16 bf16x8;
typedef __attribute__((ext_vector_type(4))) float f32x4;
typedef __attribute__((ext_vector_type(8))) ushort_t u16x8;

__device__ __forceinline__ ushort_t f2bf(float f) {
    unsigned int u = __float_as_uint(f);
    unsigned int r = (u + 0x7FFFu + ((u >> 16) & 1u)) >> 16;  // RNE
    return (ushort_t)r;
}

__device__ __forceinline__ float fast_tanh(float v) {
    float ex = __expf(2.0f * v);
    return 1.0f - __fdividef(2.0f, ex + 1.0f);
}

__device__ __forceinline__ void async_ld16(const void* g, const char* lds_uniform) {
    __builtin_amdgcn_global_load_lds(
        (const __attribute__((address_space(1))) void*)g,
        (__attribute__((address_space(3))) void*)lds_uniform,
        16, 0, 0);
}

// GEMM1 (tanh -> h_p, k-permuted [H/8][B][8]) fused with Vx. 128x128 tiles,
// BK=64, 1D grid 1152, XCD swizzle. Epilogue: LDS transpose -> 16B stores.
__global__ __launch_bounds__(256, 4)
void gemm1_vx_kernel(const ushort_t* __restrict__ xb, const ushort_t* __restrict__ W1p,
                     const ushort_t* __restrict__ Wvp, const float* __restrict__ b1,
                     ushort_t* __restrict__ hp, float* __restrict__ vxp)
{
    __shared__ __align__(16) char smem[34816];  // loop: sA 16K + sB 16K; epi: st 34K
    char* sA = smem;           // [8 kq][128 m][8] bf16 = 16 KB
    char* sB = smem + 16384;   // [8 kq][128 n][8] bf16 = 16 KB
    const int tid = threadIdx.x;
    const int lane = tid & 63;
    const int w = tid >> 6;
    const int q = lane >> 4;
    const int rlo = lane & 15;
    const int wr = w >> 1, wc = w & 1;

    const int bid = blockIdx.x;
    const int r8 = bid & 7;
    const int u = bid >> 3;       // 0..143
    const int cb = u % 18;
    const int tb = u / 18;        // 0..7
    const int row0 = (r8 + 8 * tb) * 128;

    const bool w1path = cb < 16;
    const int n0 = (w1path ? cb : cb - 16) * 128;
    const ushort_t* Bp = w1path ? W1p : Wvp;
    const int N = w1path ? H_SZ : N_SZ;

    f32x4 acc[4][4];
#pragma unroll
    for (int i = 0; i < 4; ++i)
#pragma unroll
        for (int j = 0; j < 4; ++j)
            acc[i][j] = f32x4{0.f, 0.f, 0.f, 0.f};

    for (int k0 = 0; k0 < N_SZ; k0 += 64) {
        __syncthreads();
#pragma unroll
        for (int r = 0; r < 4; ++r) {
            int c = r * 256 + tid;
            int kq = c >> 7, m = c & 127;
            async_ld16(xb + (size_t)(row0 + m) * N_SZ + k0 + kq * 8, sA + (c << 4));
        }
        int ko0 = k0 >> 3;
#pragma unroll
        for (int r = 0; r < 4; ++r) {
            int c = r * 256 + tid;
            int kq = c >> 7, n = c & 127;
            async_ld16(Bp + ((size_t)(ko0 + kq) * N + n0 + n) * 8, sB + (c << 4));
        }
        __syncthreads();

#pragma unroll
        for (int ks = 0; ks < 2; ++ks) {
            int kq = ks * 4 + q;
            bf16x8 af[4], bfr[4];
#pragma unroll
            for (int i = 0; i < 4; ++i)
                af[i] = *(const bf16x8*)(sA + (((kq << 7) + wr * 64 + i * 16 + rlo) << 4));
#pragma unroll
            for (int j = 0; j < 4; ++j)
                bfr[j] = *(const bf16x8*)(sB + (((kq << 7) + wc * 64 + j * 16 + rlo) << 4));
#pragma unroll
            for (int i = 0; i < 4; ++i)
#pragma unroll
                for (int j = 0; j < 4; ++j)
                    acc[i][j] = __builtin_amdgcn_mfma_f32_16x16x32_bf16(af[i], bfr[j], acc[i][j], 0, 0, 0);
        }
    }

    if (w1path) {
        __syncthreads();  // done with sA/sB reads; reuse LDS as transpose buffer
        ushort_t* st = (ushort_t*)smem;  // [128 rows][stride 136] bf16
#pragma unroll
        for (int j = 0; j < 4; ++j) {
            int coll = wc * 64 + j * 16 + rlo;
            float bv = b1[n0 + coll];
#pragma unroll
            for (int i = 0; i < 4; ++i) {
                int rowl = wr * 64 + i * 16 + q * 4;
#pragma unroll
                for (int rr = 0; rr < 4; ++rr)
                    st[(rowl + rr) * 136 + coll] = f2bf(fast_tanh(acc[i][j][rr] + bv));
            }
        }
        __syncthreads();
        // coalesced store: 2048 chunks x 16B -> hp[(n0/8+ko)*B + row0+m]*8
#pragma unroll
        for (int r = 0; r < 8; ++r) {
            int c = r * 256 + tid;
            int m = c & 127, ko = c >> 7;
            u16x8 v = *(const u16x8*)(st + m * 136 + ko * 8);
            *(u16x8*)(hp + ((size_t)((n0 >> 3) + ko) * B_SZ + row0 + m) * 8) = v;
        }
    } else {
        // Vx partial for col-half (n0>>7): plain store, no atomics
        float* vdst = vxp + (n0 >> 7) * B_SZ;
#pragma unroll
        for (int i = 0; i < 4; ++i) {
#pragma unroll
            for (int rr = 0; rr < 4; ++rr) {
                float s = 0.f;
#pragma unroll
                for (int j = 0; j < 4; ++j) { float v = acc[i][j][rr]; s += v * v; }
#pragma unroll
                for (int m = 1; m < 16; m <<= 1) s += __shfl_xor(s, m, 64);
                if (rlo == 0)
                    vdst[row0 + wr * 64 + i * 16 + q * 4 + rr] = s;
            }
        }
    }
}

// GEMM2: f = h@W2 + b2 (f32 only; no mub). A from hp (k-permuted).
// 64x128 tiles, BK=128 (16 iters). grid 512, XCD swizzle.
__global__ __launch_bounds__(256, 2)
void gemm2_kernel(const ushort_t* __restrict__ hp, const ushort_t* __restrict__ W2p,
                  const float* __restrict__ b2, float* __restrict__ f)
{
    __shared__ __align__(16) char smem[49152];
    char* sA = smem;           // [16 kq][64 m][8] bf16 = 16 KB
    char* sB = smem + 16384;   // [16 kq][128 n][8] bf16 = 32 KB
    const int tid = threadIdx.x;
    const int lane = tid & 63;
    const int w = tid >> 6;
    const int q = lane >> 4;
    const int rlo = lane & 15;
    const int wr = w >> 1, wc = w & 1;

    const int bid = blockIdx.x;
    const int r8 = bid & 7;
    const int u = bid >> 3;
    const int cb = u & 3;
    const int tb = u >> 2;
    const int row0 = (r8 + 8 * tb) * 64;
    const int n0 = cb * 128;

    f32x4 acc[2][4];
#pragma unroll
    for (int i = 0; i < 2; ++i)
#pragma unroll
        for (int j = 0; j < 4; ++j)
            acc[i][j] = f32x4{0.f, 0.f, 0.f, 0.f};

    for (int k0 = 0; k0 < H_SZ; k0 += 128) {
        __syncthreads();
        int ko0 = k0 >> 3;
#pragma unroll
        for (int r = 0; r < 4; ++r) {   // A: 1024 chunks from hp, [kq][m][8]
            int c = r * 256 + tid;
            int kq = c >> 6, m = c & 63;
            async_ld16(hp + ((size_t)(ko0 + kq) * B_SZ + row0 + m) * 8, sA + (c << 4));
        }
#pragma unroll
        for (int r = 0; r < 8; ++r) {   // B: 2048 chunks, [kq][n][8]
            int c = r * 256 + tid;
            int kq = c >> 7, n = c & 127;
            async_ld16(W2p + ((size_t)(ko0 + kq) * 512 + n0 + n) * 8, sB + (c << 4));
        }
        __syncthreads();

#pragma unroll
        for (int ks = 0; ks < 4; ++ks) {
            int kq = ks * 4 + q;
            bf16x8 af[2], bfr[4];
#pragma unroll
            for (int i = 0; i < 2; ++i)
                af[i] = *(const bf16x8*)(sA + (((kq << 6) + wr * 32 + i * 16 + rlo) << 4));
#pragma unroll
            for (int j = 0; j < 4; ++j)
                bfr[j] = *(const bf16x8*)(sB + (((kq << 7) + wc * 64 + j * 16 + rlo) << 4));
#pragma unroll
            for (int i = 0; i < 2; ++i)
#pragma unroll
                for (int j = 0; j < 4; ++j)
                    acc[i][j] = __builtin_amdgcn_mfma_f32_16x16x32_bf16(af[i], bfr[j], acc[i][j], 0, 0, 0);
        }
    }

#pragma unroll
    for (int j = 0; j < 4; ++j) {
        int col = n0 + wc * 64 + j * 16 + rlo;
        float bv = b2[col];
#pragma unroll
        for (int i = 0; i < 2; ++i) {
            int rowb = row0 + wr * 32 + i * 16 + q * 4;
#pragma unroll
            for (int rr = 0; rr < 4; ++rr)
                f[(size_t)(rowb + rr) * 512 + col] = acc[i][j][rr] + bv;
        }
    }
}

// Fused Vmu + epilogue + final reduce (last-block), 512 blocks x 16 rows.
// Stage 1: mu read from f (f32 -> bf16 inline), Vmu via MFMA.
__global__ __launch_bounds__(256)
void vmu_epilogue_kernel(const ushort_t* __restrict__ Wvp,
                         const float* __restrict__ f, const float* __restrict__ y,
                         const float* __restrict__ eps, const float* __restrict__ vxp,
                         float* __restrict__ out, float* __restrict__ partials,
                         unsigned int* __restrict__ counter)
{
    __shared__ float vsum[4][16];
    __shared__ float vmu_s[16];
    __shared__ float red[4];
    __shared__ unsigned int done_s;
    const int tid = threadIdx.x;
    const int lane = tid & 63;
    const int w = tid >> 6;
    const int q = lane >> 4;
    const int rlo = lane & 15;
    const int r0 = blockIdx.x * 16;

    // ---- stage 1: Vmu via MFMA (16x64 tile per wave), A from f (f32) ----
    f32x4 acc[4];
#pragma unroll
    for (int j = 0; j < 4; ++j)
        acc[j] = f32x4{0.f, 0.f, 0.f, 0.f};

    const float* fa = f + (size_t)(r0 + rlo) * 512 + q * 8;
    const ushort_t* b0 = Wvp + ((size_t)q * N_SZ + w * 64 + rlo) * 8;
#pragma unroll
    for (int s = 0; s < 8; ++s) {
        f32x4 v0 = *(const f32x4*)(fa + s * 32);
        f32x4 v1 = *(const f32x4*)(fa + s * 32 + 4);
        u16x8 a;
#pragma unroll
        for (int e = 0; e < 4; ++e) { a[e] = f2bf(v0[e]); a[4 + e] = f2bf(v1[e]); }
        bf16x8 af = *(const bf16x8*)&a;
        bf16x8 bfr[4];
#pragma unroll
        for (int j = 0; j < 4; ++j)
            bfr[j] = *(const bf16x8*)(b0 + s * 4 * N_SZ * 8 + j * 128);
#pragma unroll
        for (int j = 0; j < 4; ++j)
            acc[j] = __builtin_amdgcn_mfma_f32_16x16x32_bf16(af, bfr[j], acc[j], 0, 0, 0);
    }
#pragma unroll
    for (int rr = 0; rr < 4; ++rr) {
        float s = 0.f;
#pragma unroll
        for (int j = 0; j < 4; ++j) { float v = acc[j][rr]; s += v * v; }
#pragma unroll
        for (int m = 1; m < 16; m <<= 1) s += __shfl_xor(s, m, 64);
        if (rlo == 0) vsum[w][q * 4 + rr] = s;
    }
    __syncthreads();
    if (tid < 16)
        vmu_s[tid] = 1e-3f + vsum[0][tid] + vsum[1][tid] + vsum[2][tid] + vsum[3][tid];
    __syncthreads();

    // ---- stage 2: epilogue over 16 rows ----
    float t = 0.f;
    const int n = tid;
#pragma unroll 4
    for (int r = 0; r < 16; ++r) {
        size_t row = (size_t)(r0 + r);
        float mu = f[row * 512 + n];
        float lv = f[row * 512 + 256 + n];
        float var = expf(lv);
        float Vx = vxp[row] + vxp[B_SZ + row] + 1e-3f;
        float Vmu = vmu_s[r];
        float scale = fminf(BETA_F * Vx, Vmu) / Vmu;
        float mus = mu * scale;
        out[row * 256 + n] = mus + sqrtf(var) * eps[row * 256 + n];
        float d = y[row * 256 + n] - mus;
        t += lv + d * d / var;
    }
#pragma unroll
    for (int m = 32; m >= 1; m >>= 1) t += __shfl_down(t, m, 64);
    if (lane == 0) red[w] = t;
    __syncthreads();
    if (tid == 0) {
        partials[blockIdx.x] = red[0] + red[1] + red[2] + red[3];
        __threadfence();
        done_s = atomicAdd(counter, 1u);
    }
    __syncthreads();
    if (done_s == 511u) {  // last block: final reduction of 512 partials
        float s = partials[tid] + partials[tid + 256];
#pragma unroll
        for (int m = 32; m >= 1; m >>= 1) s += __shfl_down(s, m, 64);
        if (lane == 0) red[w] = s;
        __syncthreads();
        if (tid == 0)
            out[(size_t)B_SZ * N_SZ] =
                0.5f * (red[0] + red[1] + red[2] + red[3] +
                        (float)N_SZ * LOG2PI_F * (float)B_SZ);
    }
}

// Conversion, fully coalesced: one thread per 8-element k-chunk.
__global__ __launch_bounds__(256)
void convert_kernel(const float* __restrict__ x, const float* __restrict__ W1,
                    const float* __restrict__ W2, const float* __restrict__ Wv,
                    ushort_t* __restrict__ xb, ushort_t* __restrict__ W1p,
                    ushort_t* __restrict__ W2p, ushort_t* __restrict__ Wvp)
{
    const int XC = 262144, W1C = 65536, W2C = 131072;
    int c = blockIdx.x * 256 + threadIdx.x;
    if (c < XC) {
        f32x4 a = *(const f32x4*)(x + (size_t)c * 8);
        f32x4 b = *(const f32x4*)(x + (size_t)c * 8 + 4);
        u16x8 o;
#pragma unroll
        for (int i = 0; i < 4; ++i) { o[i] = f2bf(a[i]); o[4 + i] = f2bf(b[i]); }
        *(u16x8*)(xb + (size_t)c * 8) = o;
    } else if (c < XC + W1C) {
        int d = c - XC;
        int ko = d >> 11, n = d & 2047;
        u16x8 o;
#pragma unroll
        for (int ki = 0; ki < 8; ++ki)
            o[ki] = f2bf(W1[(size_t)(ko * 8 + ki) * H_SZ + n]);
        *(u16x8*)(W1p + (size_t)d * 8) = o;
    } else if (c < XC + W1C + W2C) {
        int d = c - XC - W1C;
        int ko = d >> 9, n = d & 511;
        u16x8 o;
#pragma unroll
        for (int ki = 0; ki < 8; ++ki)
            o[ki] = f2bf(W2[(size_t)(ko * 8 + ki) * 512 + n]);
        *(u16x8*)(W2p + (size_t)d * 8) = o;
    } else {
        int d = c - XC - W1C - W2C;
        int ko = d >> 8, n = d & 255;
        u16x8 o;
#pragma unroll
        for (int ki = 0; ki < 8; ++ki)
            o[ki] = f2bf(Wv[(size_t)(ko * 8 + ki) * N_SZ + n]);
        *(u16x8*)(Wvp + (size_t)d * 8) = o;
    }
}

extern "C" void kernel_launch(void* const* d_in, const int* in_sizes, int n_in,
                              void* d_out, int out_size, void* d_ws, size_t ws_size,
                              hipStream_t stream)
{
    const float* x   = (const float*)d_in[0];
    const float* y   = (const float*)d_in[1];
    const float* eps = (const float*)d_in[2];
    const float* W1  = (const float*)d_in[3];
    const float* b1  = (const float*)d_in[4];
    const float* W2  = (const float*)d_in[5];
    const float* b2  = (const float*)d_in[6];
    const float* Wv  = (const float*)d_in[7];
    float* out = (float*)d_out;

    char* ws = (char*)d_ws;
    size_t off = 0;
    auto alloc = [&](size_t bytes) {
        char* p = ws + off;
        off += (bytes + 255) & ~(size_t)255;
        return p;
    };
    ushort_t* xb  = (ushort_t*)alloc((size_t)B_SZ * N_SZ * 2);
    ushort_t* W1p = (ushort_t*)alloc((size_t)N_SZ * H_SZ * 2);
    ushort_t* W2p = (ushort_t*)alloc((size_t)H_SZ * 512 * 2);
    ushort_t* Wvp = (ushort_t*)alloc((size_t)N_SZ * N_SZ * 2);
    ushort_t* hp  = (ushort_t*)alloc((size_t)B_SZ * H_SZ * 2);
    float*    f   = (float*)alloc((size_t)B_SZ * 512 * 4);
    float*    vxp = (float*)alloc((size_t)2 * B_SZ * 4);
    float*    partials = (float*)alloc(512 * 4);
    unsigned int* counter = (unsigned int*)alloc(256);

    hipMemsetAsync(counter, 0, 4, stream);

    const int TOTALC = 262144 + 65536 + 131072 + 8192;  // 466944 chunks
    convert_kernel<<<TOTALC / 256, 256, 0, stream>>>(x, W1, W2, Wv, xb, W1p, W2p, Wvp);

    // h_p = tanh(x@W1 + b1) k-permuted (+ fused Vx partials), BK=64
    gemm1_vx_kernel<<<1152, 256, 0, stream>>>(xb, W1p, Wvp, b1, hp, vxp);
    // f = h@W2 + b2, BK=128, A from hp
    gemm2_kernel<<<512, 256, 0, stream>>>(hp, W2p, b2, f);
    // Vmu + epilogue + final reduce fused, 512 blocks
    vmu_epilogue_kernel<<<512, 256, 0, stream>>>(Wvp, f, y, eps, vxp, out, partials, counter);
}

// Round 15
// 153.922 us; speedup vs baseline: 1.0785x; 1.0785x over previous
//
#include <hip/hip_runtime.h>
#include <stdint.h>

#define B_SZ 8192
#define N_SZ 256
#define H_SZ 2048
#define LOG2PI_F 1.8378770664093453f
#define BETA_F 0.99f

typedef unsigned short ushort_t;
typedef __attribute__((ext_vector_type(8))) __bf16 bf16x8;
typedef __attribute__((ext_vector_type(4))) float f32x4;
typedef __attribute__((ext_vector_type(8))) ushort_t u16x8;

__device__ __forceinline__ ushort_t f2bf(float f) {
    unsigned int u = __float_as_uint(f);
    unsigned int r = (u + 0x7FFFu + ((u >> 16) & 1u)) >> 16;  // RNE
    return (ushort_t)r;
}

__device__ __forceinline__ float fast_tanh(float v) {
    float ex = __expf(2.0f * v);
    return 1.0f - __fdividef(2.0f, ex + 1.0f);
}

__device__ __forceinline__ void async_ld16(const void* g, const char* lds_uniform) {
    __builtin_amdgcn_global_load_lds(
        (const __attribute__((address_space(1))) void*)g,
        (__attribute__((address_space(3))) void*)lds_uniform,
        16, 0, 0);
}

// GEMM1 (tanh -> h_p, k-permuted [H/8][B][8]) fused with Vx. 128x128 tiles,
// BK=64, 1D grid 1152, XCD swizzle. Epilogue: LDS transpose -> 16B stores.
__global__ __launch_bounds__(256, 4)
void gemm1_vx_kernel(const ushort_t* __restrict__ xb, const ushort_t* __restrict__ W1p,
                     const ushort_t* __restrict__ Wvp, const float* __restrict__ b1,
                     ushort_t* __restrict__ hp, float* __restrict__ vxp)
{
    __shared__ __align__(16) char smem[34816];  // loop: sA 16K + sB 16K; epi: st 34K
    char* sA = smem;           // [8 kq][128 m][8] bf16 = 16 KB
    char* sB = smem + 16384;   // [8 kq][128 n][8] bf16 = 16 KB
    const int tid = threadIdx.x;
    const int lane = tid & 63;
    const int w = tid >> 6;
    const int q = lane >> 4;
    const int rlo = lane & 15;
    const int wr = w >> 1, wc = w & 1;

    const int bid = blockIdx.x;
    const int r8 = bid & 7;
    const int u = bid >> 3;       // 0..143
    const int cb = u % 18;
    const int tb = u / 18;        // 0..7
    const int row0 = (r8 + 8 * tb) * 128;

    const bool w1path = cb < 16;
    const int n0 = (w1path ? cb : cb - 16) * 128;
    const ushort_t* Bp = w1path ? W1p : Wvp;
    const int N = w1path ? H_SZ : N_SZ;

    f32x4 acc[4][4];
#pragma unroll
    for (int i = 0; i < 4; ++i)
#pragma unroll
        for (int j = 0; j < 4; ++j)
            acc[i][j] = f32x4{0.f, 0.f, 0.f, 0.f};

    for (int k0 = 0; k0 < N_SZ; k0 += 64) {
        __syncthreads();
#pragma unroll
        for (int r = 0; r < 4; ++r) {
            int c = r * 256 + tid;
            int kq = c >> 7, m = c & 127;
            async_ld16(xb + (size_t)(row0 + m) * N_SZ + k0 + kq * 8, sA + (c << 4));
        }
        int ko0 = k0 >> 3;
#pragma unroll
        for (int r = 0; r < 4; ++r) {
            int c = r * 256 + tid;
            int kq = c >> 7, n = c & 127;
            async_ld16(Bp + ((size_t)(ko0 + kq) * N + n0 + n) * 8, sB + (c << 4));
        }
        __syncthreads();

#pragma unroll
        for (int ks = 0; ks < 2; ++ks) {
            int kq = ks * 4 + q;
            bf16x8 af[4], bfr[4];
#pragma unroll
            for (int i = 0; i < 4; ++i)
                af[i] = *(const bf16x8*)(sA + (((kq << 7) + wr * 64 + i * 16 + rlo) << 4));
#pragma unroll
            for (int j = 0; j < 4; ++j)
                bfr[j] = *(const bf16x8*)(sB + (((kq << 7) + wc * 64 + j * 16 + rlo) << 4));
#pragma unroll
            for (int i = 0; i < 4; ++i)
#pragma unroll
                for (int j = 0; j < 4; ++j)
                    acc[i][j] = __builtin_amdgcn_mfma_f32_16x16x32_bf16(af[i], bfr[j], acc[i][j], 0, 0, 0);
        }
    }

    if (w1path) {
        __syncthreads();  // done with sA/sB reads; reuse LDS as transpose buffer
        ushort_t* st = (ushort_t*)smem;  // [128 rows][stride 136] bf16
#pragma unroll
        for (int j = 0; j < 4; ++j) {
            int coll = wc * 64 + j * 16 + rlo;
            float bv = b1[n0 + coll];
#pragma unroll
            for (int i = 0; i < 4; ++i) {
                int rowl = wr * 64 + i * 16 + q * 4;
#pragma unroll
                for (int rr = 0; rr < 4; ++rr)
                    st[(rowl + rr) * 136 + coll] = f2bf(fast_tanh(acc[i][j][rr] + bv));
            }
        }
        __syncthreads();
        // coalesced store: 2048 chunks x 16B -> hp[(n0/8+ko)*B + row0+m]*8
#pragma unroll
        for (int r = 0; r < 8; ++r) {
            int c = r * 256 + tid;
            int m = c & 127, ko = c >> 7;
            u16x8 v = *(const u16x8*)(st + m * 136 + ko * 8);
            *(u16x8*)(hp + ((size_t)((n0 >> 3) + ko) * B_SZ + row0 + m) * 8) = v;
        }
    } else {
        // Vx partial for col-half (n0>>7): plain store, no atomics
        float* vdst = vxp + (n0 >> 7) * B_SZ;
#pragma unroll
        for (int i = 0; i < 4; ++i) {
#pragma unroll
            for (int rr = 0; rr < 4; ++rr) {
                float s = 0.f;
#pragma unroll
                for (int j = 0; j < 4; ++j) { float v = acc[i][j][rr]; s += v * v; }
#pragma unroll
                for (int m = 1; m < 16; m <<= 1) s += __shfl_xor(s, m, 64);
                if (rlo == 0)
                    vdst[row0 + wr * 64 + i * 16 + q * 4 + rr] = s;
            }
        }
    }
}

// GEMM2: f = h@W2 + b2, mub = bf16(f[:, :256]) via LDS-transposed 16B stores.
// A from hp (k-permuted). 64x128 tiles, BK=128 (16 iters). grid 512, XCD swizzle.
__global__ __launch_bounds__(256, 2)
void gemm2_kernel(const ushort_t* __restrict__ hp, const ushort_t* __restrict__ W2p,
                  const float* __restrict__ b2, float* __restrict__ f,
                  ushort_t* __restrict__ mub)
{
    __shared__ __align__(16) char smem[49152];
    char* sA = smem;           // [16 kq][64 m][8] bf16 = 16 KB
    char* sB = smem + 16384;   // [16 kq][128 n][8] bf16 = 32 KB
    const int tid = threadIdx.x;
    const int lane = tid & 63;
    const int w = tid >> 6;
    const int q = lane >> 4;
    const int rlo = lane & 15;
    const int wr = w >> 1, wc = w & 1;

    const int bid = blockIdx.x;
    const int r8 = bid & 7;
    const int u = bid >> 3;
    const int cb = u & 3;
    const int tb = u >> 2;
    const int row0 = (r8 + 8 * tb) * 64;
    const int n0 = cb * 128;

    f32x4 acc[2][4];
#pragma unroll
    for (int i = 0; i < 2; ++i)
#pragma unroll
        for (int j = 0; j < 4; ++j)
            acc[i][j] = f32x4{0.f, 0.f, 0.f, 0.f};

    for (int k0 = 0; k0 < H_SZ; k0 += 128) {
        __syncthreads();
        int ko0 = k0 >> 3;
#pragma unroll
        for (int r = 0; r < 4; ++r) {   // A: 1024 chunks from hp, [kq][m][8]
            int c = r * 256 + tid;
            int kq = c >> 6, m = c & 63;
            async_ld16(hp + ((size_t)(ko0 + kq) * B_SZ + row0 + m) * 8, sA + (c << 4));
        }
#pragma unroll
        for (int r = 0; r < 8; ++r) {   // B: 2048 chunks, [kq][n][8]
            int c = r * 256 + tid;
            int kq = c >> 7, n = c & 127;
            async_ld16(W2p + ((size_t)(ko0 + kq) * 512 + n0 + n) * 8, sB + (c << 4));
        }
        __syncthreads();

#pragma unroll
        for (int ks = 0; ks < 4; ++ks) {
            int kq = ks * 4 + q;
            bf16x8 af[2], bfr[4];
#pragma unroll
            for (int i = 0; i < 2; ++i)
                af[i] = *(const bf16x8*)(sA + (((kq << 6) + wr * 32 + i * 16 + rlo) << 4));
#pragma unroll
            for (int j = 0; j < 4; ++j)
                bfr[j] = *(const bf16x8*)(sB + (((kq << 7) + wc * 64 + j * 16 + rlo) << 4));
#pragma unroll
            for (int i = 0; i < 2; ++i)
#pragma unroll
                for (int j = 0; j < 4; ++j)
                    acc[i][j] = __builtin_amdgcn_mfma_f32_16x16x32_bf16(af[i], bfr[j], acc[i][j], 0, 0, 0);
        }
    }

    // f32 stores (clean 64B segments per quad)
#pragma unroll
    for (int j = 0; j < 4; ++j) {
        int col = n0 + wc * 64 + j * 16 + rlo;
        float bv = b2[col];
#pragma unroll
        for (int i = 0; i < 2; ++i) {
            int rowb = row0 + wr * 32 + i * 16 + q * 4;
#pragma unroll
            for (int rr = 0; rr < 4; ++rr)
                f[(size_t)(rowb + rr) * 512 + col] = acc[i][j][rr] + bv;
        }
    }
    // mub (cols < 256 only, i.e. cb 0/1): LDS transpose -> coalesced 16B stores
    if (n0 < N_SZ) {
        __syncthreads();  // all waves done reading sA/sB
        ushort_t* st = (ushort_t*)smem;  // [64 rows][stride 136] bf16
#pragma unroll
        for (int j = 0; j < 4; ++j) {
            int coll = wc * 64 + j * 16 + rlo;
            float bv = b2[n0 + coll];
#pragma unroll
            for (int i = 0; i < 2; ++i) {
                int rowl = wr * 32 + i * 16 + q * 4;
#pragma unroll
                for (int rr = 0; rr < 4; ++rr)
                    st[(rowl + rr) * 136 + coll] = f2bf(acc[i][j][rr] + bv);
            }
        }
        __syncthreads();
        // 1024 chunks x 16B: chunk c -> row c>>4, col8 c&15 (256B contig/row)
#pragma unroll
        for (int r = 0; r < 4; ++r) {
            int c = r * 256 + tid;
            int m = c >> 4, c8 = c & 15;
            u16x8 v = *(const u16x8*)(st + m * 136 + c8 * 8);
            *(u16x8*)(mub + (size_t)(row0 + m) * N_SZ + n0 + c8 * 8) = v;
        }
    }
}

// Fused Vmu + epilogue, 512 blocks x 16 rows.
__global__ __launch_bounds__(256)
void vmu_epilogue_kernel(const ushort_t* __restrict__ mub, const ushort_t* __restrict__ Wvp,
                         const float* __restrict__ f, const float* __restrict__ y,
                         const float* __restrict__ eps, const float* __restrict__ vxp,
                         float* __restrict__ out, float* __restrict__ partials)
{
    __shared__ float vsum[4][16];
    __shared__ float vmu_s[16];
    __shared__ float red[4];
    const int tid = threadIdx.x;
    const int lane = tid & 63;
    const int w = tid >> 6;
    const int q = lane >> 4;
    const int rlo = lane & 15;
    const int r0 = blockIdx.x * 16;

    // ---- stage 1: Vmu via MFMA (16x64 tile per wave) ----
    f32x4 acc[4];
#pragma unroll
    for (int j = 0; j < 4; ++j)
        acc[j] = f32x4{0.f, 0.f, 0.f, 0.f};

    const ushort_t* a0 = mub + (size_t)(r0 + rlo) * N_SZ + q * 8;
    const ushort_t* b0 = Wvp + ((size_t)q * N_SZ + w * 64 + rlo) * 8;
#pragma unroll
    for (int s = 0; s < 8; ++s) {
        bf16x8 af = *(const bf16x8*)(a0 + s * 32);
        bf16x8 bfr[4];
#pragma unroll
        for (int j = 0; j < 4; ++j)
            bfr[j] = *(const bf16x8*)(b0 + s * 4 * N_SZ * 8 + j * 128);
#pragma unroll
        for (int j = 0; j < 4; ++j)
            acc[j] = __builtin_amdgcn_mfma_f32_16x16x32_bf16(af, bfr[j], acc[j], 0, 0, 0);
    }
#pragma unroll
    for (int rr = 0; rr < 4; ++rr) {
        float s = 0.f;
#pragma unroll
        for (int j = 0; j < 4; ++j) { float v = acc[j][rr]; s += v * v; }
#pragma unroll
        for (int m = 1; m < 16; m <<= 1) s += __shfl_xor(s, m, 64);
        if (rlo == 0) vsum[w][q * 4 + rr] = s;
    }
    __syncthreads();
    if (tid < 16)
        vmu_s[tid] = 1e-3f + vsum[0][tid] + vsum[1][tid] + vsum[2][tid] + vsum[3][tid];
    __syncthreads();

    // ---- stage 2: epilogue over 16 rows ----
    float t = 0.f;
    const int n = tid;
#pragma unroll 4
    for (int r = 0; r < 16; ++r) {
        size_t row = (size_t)(r0 + r);
        float mu = f[row * 512 + n];
        float lv = f[row * 512 + 256 + n];
        float var = expf(lv);
        float Vx = vxp[row] + vxp[B_SZ + row] + 1e-3f;
        float Vmu = vmu_s[r];
        float scale = fminf(BETA_F * Vx, Vmu) / Vmu;
        float mus = mu * scale;
        out[row * 256 + n] = mus + sqrtf(var) * eps[row * 256 + n];
        float d = y[row * 256 + n] - mus;
        t += lv + d * d / var;
    }
#pragma unroll
    for (int m = 32; m >= 1; m >>= 1) t += __shfl_down(t, m, 64);
    if (lane == 0) red[w] = t;
    __syncthreads();
    if (tid == 0)
        partials[blockIdx.x] = red[0] + red[1] + red[2] + red[3];
}

// sum 512 partials -> logp_y scalar.
__global__ __launch_bounds__(256)
void reduce_kernel(const float* __restrict__ partials, float* __restrict__ out)
{
    int tid = threadIdx.x;
    float s = partials[tid] + partials[tid + 256];
#pragma unroll
    for (int m = 32; m >= 1; m >>= 1) s += __shfl_down(s, m, 64);
    __shared__ float red[4];
    if ((tid & 63) == 0) red[tid >> 6] = s;
    __syncthreads();
    if (tid == 0)
        out[(size_t)B_SZ * N_SZ] =
            0.5f * (red[0] + red[1] + red[2] + red[3] +
                    (float)N_SZ * LOG2PI_F * (float)B_SZ);
}

// Conversion, fully coalesced: one thread per 8-element k-chunk.
__global__ __launch_bounds__(256)
void convert_kernel(const float* __restrict__ x, const float* __restrict__ W1,
                    const float* __restrict__ W2, const float* __restrict__ Wv,
                    ushort_t* __restrict__ xb, ushort_t* __restrict__ W1p,
                    ushort_t* __restrict__ W2p, ushort_t* __restrict__ Wvp)
{
    const int XC = 262144, W1C = 65536, W2C = 131072;
    int c = blockIdx.x * 256 + threadIdx.x;
    if (c < XC) {
        f32x4 a = *(const f32x4*)(x + (size_t)c * 8);
        f32x4 b = *(const f32x4*)(x + (size_t)c * 8 + 4);
        u16x8 o;
#pragma unroll
        for (int i = 0; i < 4; ++i) { o[i] = f2bf(a[i]); o[4 + i] = f2bf(b[i]); }
        *(u16x8*)(xb + (size_t)c * 8) = o;
    } else if (c < XC + W1C) {
        int d = c - XC;
        int ko = d >> 11, n = d & 2047;
        u16x8 o;
#pragma unroll
        for (int ki = 0; ki < 8; ++ki)
            o[ki] = f2bf(W1[(size_t)(ko * 8 + ki) * H_SZ + n]);
        *(u16x8*)(W1p + (size_t)d * 8) = o;
    } else if (c < XC + W1C + W2C) {
        int d = c - XC - W1C;
        int ko = d >> 9, n = d & 511;
        u16x8 o;
#pragma unroll
        for (int ki = 0; ki < 8; ++ki)
            o[ki] = f2bf(W2[(size_t)(ko * 8 + ki) * 512 + n]);
        *(u16x8*)(W2p + (size_t)d * 8) = o;
    } else {
        int d = c - XC - W1C - W2C;
        int ko = d >> 8, n = d & 255;
        u16x8 o;
#pragma unroll
        for (int ki = 0; ki < 8; ++ki)
            o[ki] = f2bf(Wv[(size_t)(ko * 8 + ki) * N_SZ + n]);
        *(u16x8*)(Wvp + (size_t)d * 8) = o;
    }
}

extern "C" void kernel_launch(void* const* d_in, const int* in_sizes, int n_in,
                              void* d_out, int out_size, void* d_ws, size_t ws_size,
                              hipStream_t stream)
{
    const float* x   = (const float*)d_in[0];
    const float* y   = (const float*)d_in[1];
    const float* eps = (const float*)d_in[2];
    const float* W1  = (const float*)d_in[3];
    const float* b1  = (const float*)d_in[4];
    const float* W2  = (const float*)d_in[5];
    const float* b2  = (const float*)d_in[6];
    const float* Wv  = (const float*)d_in[7];
    float* out = (float*)d_out;

    char* ws = (char*)d_ws;
    size_t off = 0;
    auto alloc = [&](size_t bytes) {
        char* p = ws + off;
        off += (bytes + 255) & ~(size_t)255;
        return p;
    };
    ushort_t* xb  = (ushort_t*)alloc((size_t)B_SZ * N_SZ * 2);
    ushort_t* W1p = (ushort_t*)alloc((size_t)N_SZ * H_SZ * 2);
    ushort_t* W2p = (ushort_t*)alloc((size_t)H_SZ * 512 * 2);
    ushort_t* Wvp = (ushort_t*)alloc((size_t)N_SZ * N_SZ * 2);
    ushort_t* hp  = (ushort_t*)alloc((size_t)B_SZ * H_SZ * 2);
    float*    f   = (float*)alloc((size_t)B_SZ * 512 * 4);
    ushort_t* mub = (ushort_t*)alloc((size_t)B_SZ * N_SZ * 2);
    float*    vxp = (float*)alloc((size_t)2 * B_SZ * 4);
    float*    partials = (float*)alloc(512 * 4);

    const int TOTALC = 262144 + 65536 + 131072 + 8192;  // 466944 chunks
    convert_kernel<<<TOTALC / 256, 256, 0, stream>>>(x, W1, W2, Wv, xb, W1p, W2p, Wvp);

    // h_p = tanh(x@W1 + b1) k-permuted (+ fused Vx partials), BK=64
    gemm1_vx_kernel<<<1152, 256, 0, stream>>>(xb, W1p, Wvp, b1, hp, vxp);
    // f = h@W2 + b2 ; mub via LDS transpose, BK=128, A from hp
    gemm2_kernel<<<512, 256, 0, stream>>>(hp, W2p, b2, f, mub);
    // Vmu + epilogue fused, 512 blocks
    vmu_epilogue_kernel<<<512, 256, 0, stream>>>(mub, Wvp, f, y, eps, vxp, out, partials);
    reduce_kernel<<<1, 256, 0, stream>>>(partials, out);
}